// Round 15
// baseline (275.149 us; speedup 1.0000x reference)
//
#include <hip/hip_runtime.h>

#define NN  8193       // output cols per row; u length
#define FN  16384      // complex FFT length (real conv length 32768)
#define NTHR 1024      // threads per FFT block

// LDS swizzle-pad (R12/R14-verified): injective. Max ZIDX(16383) = 17676.
#define ZIDX(i) ((i) + ((i) >> 4) + ((i) >> 6) + ((i) >> 10))
#define ZPAD 17680

// workspace byte offsets (256-aligned)
#define OFF_BANDS 0u        // 3*2049*4
#define OFF_AF32  24832u    // 16385*4
#define OFF_AHAT  90624u    // 16385*8
#define OFF_TW    221952u   // 4096*8 = 32768 (w_N^e, e in [0,4096) — L1-resident)
#define OFF_TAU   320256u   // 16385*8 (exp(-i pi k/N))

__device__ __forceinline__ float2 cmul(float2 a, float2 b) {
  return make_float2(a.x * b.x - a.y * b.y, a.x * b.y + a.y * b.x);
}
__device__ __forceinline__ float2 cadd(float2 a, float2 b) { return make_float2(a.x + b.x, a.y + b.y); }
__device__ __forceinline__ float2 csub(float2 a, float2 b) { return make_float2(a.x - b.x, a.y - b.y); }

// base-4 digit reversal of 7 digits (14 bits)
__device__ __forceinline__ int rev4_14(int k) {
  int r = 0;
  #pragma unroll
  for (int i = 0; i < 7; ++i) { r = (r << 2) | (k & 3); k >>= 2; }
  return r;
}

// Single radix-4 stage with affine swizzled offsets (R14-verified, incl. carry
// analysis: ZIDX(base + k*Q) = ZIDX(base) + ZO*k for each stage's base range).
template<int Q, int M, bool INV>
__device__ __forceinline__ void stage4(float2* Z, const float2* __restrict__ tw,
                                       int tid) {
  constexpr int ZO = (Q == 1024) ? 1105 : (Q == 256) ? 276
                   : (Q == 64)   ? 69   : (Q == 16)  ? 17  : 4;
  #pragma unroll 1
  for (int r = 0; r < FN / 4 / NTHR; ++r) {
    const int idx = tid + r * NTHR;
    const int j  = idx & (Q - 1);
    const int b1 = idx / Q;
    const int z0 = ZIDX(b1 * 4 * Q + j);
    float2 w1 = tw[j * M];
    if (INV) w1.y = -w1.y;
    const float2 w2 = cmul(w1, w1);
    const float2 w3 = cmul(w1, w2);
    if (!INV) {
      float2 c0 = Z[z0], c1 = Z[z0 + ZO], c2 = Z[z0 + 2 * ZO], c3 = Z[z0 + 3 * ZO];
      float2 t0 = cadd(c0, c2), t1 = csub(c0, c2), t2 = cadd(c1, c3);
      float2 t3 = make_float2(c1.y - c3.y, -(c1.x - c3.x));   // -i*(c1-c3)
      Z[z0]          = cadd(t0, t2);
      Z[z0 + ZO]     = cmul(w1, cadd(t1, t3));
      Z[z0 + 2 * ZO] = cmul(w2, csub(t0, t2));
      Z[z0 + 3 * ZO] = cmul(w3, csub(t1, t3));
    } else {
      float2 u0 = Z[z0];
      float2 u1 = cmul(w1, Z[z0 + ZO]);
      float2 u2 = cmul(w2, Z[z0 + 2 * ZO]);
      float2 u3 = cmul(w3, Z[z0 + 3 * ZO]);
      float2 s0 = cadd(u0, u2), s1 = csub(u0, u2), s2 = cadd(u1, u3);
      float2 s3 = make_float2(-(u1.y - u3.y), u1.x - u3.x);   // +i*(u1-u3)
      Z[z0]          = cadd(s0, s2);
      Z[z0 + ZO]     = cadd(s1, s3);
      Z[z0 + 2 * ZO] = csub(s0, s2);
      Z[z0 + 3 * ZO] = csub(s1, s3);
    }
  }
}

// stage 6 (Q=1): all twiddles = 1
__device__ __forceinline__ void s6_fwd(float2* Z, int tid) {
  #pragma unroll 1
  for (int m = tid; m < FN / 4; m += NTHR) {
    const int zb = 4 * m + (m >> 2) + (m >> 4) + (m >> 8);
    float2 c0 = Z[zb], c1 = Z[zb + 1], c2 = Z[zb + 2], c3 = Z[zb + 3];
    float2 t0 = cadd(c0, c2), t1 = csub(c0, c2), t2 = cadd(c1, c3);
    float2 t3 = make_float2(c1.y - c3.y, -(c1.x - c3.x));
    Z[zb]     = cadd(t0, t2);
    Z[zb + 1] = cadd(t1, t3);
    Z[zb + 2] = csub(t0, t2);
    Z[zb + 3] = csub(t1, t3);
  }
}
__device__ __forceinline__ void s6_inv(float2* Z, int tid) {
  #pragma unroll 1
  for (int m = tid; m < FN / 4; m += NTHR) {
    const int zb = 4 * m + (m >> 2) + (m >> 4) + (m >> 8);
    float2 u0 = Z[zb], u1 = Z[zb + 1], u2 = Z[zb + 2], u3 = Z[zb + 3];
    float2 s0 = cadd(u0, u2), s1 = csub(u0, u2), s2 = cadd(u1, u3);
    float2 s3 = make_float2(-(u1.y - u3.y), u1.x - u3.x);
    Z[zb]     = cadd(s0, s2);
    Z[zb + 1] = cadd(s1, s3);
    Z[zb + 2] = csub(s0, s2);
    Z[zb + 3] = csub(s1, s3);
  }
}

// forward stages 1..6 (after the fused first stage)
__device__ void fft_fwd_rest(float2* Z, const float2* __restrict__ tw, int tid) {
  stage4<1024, 4, false>(Z, tw, tid);   __syncthreads();
  stage4<256, 16, false>(Z, tw, tid);   __syncthreads();
  stage4<64, 64, false>(Z, tw, tid);    __syncthreads();
  stage4<16, 256, false>(Z, tw, tid);   __syncthreads();
  stage4<4, 1024, false>(Z, tw, tid);   __syncthreads();
  s6_fwd(Z, tid);                       __syncthreads();
}
// inverse stages up to (but excluding) the final Q=4096 stage
__device__ void fft_inv_rest(float2* Z, const float2* __restrict__ tw, int tid) {
  s6_inv(Z, tid);                       __syncthreads();
  stage4<4, 1024, true>(Z, tw, tid);    __syncthreads();
  stage4<16, 256, true>(Z, tw, tid);    __syncthreads();
  stage4<64, 64, true>(Z, tw, tid);     __syncthreads();
  stage4<256, 16, true>(Z, tw, tid);    __syncthreads();
  stage4<1024, 4, true>(Z, tw, tid);    __syncthreads();
}

// twiddle tables
__global__ void k_tw(float2* __restrict__ tw, float2* __restrict__ tau) {
  const int i = blockIdx.x * 256 + threadIdx.x;
  if (i < 4096) {
    const float ang = -6.283185307179586f * (float)i / 16384.0f;
    tw[i] = make_float2(cosf(ang), sinf(ang));
  }
  if (i <= 16384) {
    const float ang = -3.1415926535897932f * (float)i / 16384.0f;
    tau[i] = make_float2(cosf(ang), sinf(ang));
  }
}

// ---------------- kernel a construction (unchanged) ----------
__global__ void k_bands(const float* __restrict__ x,
                        const float* __restrict__ W1, const float* __restrict__ b1,
                        const float* __restrict__ W2, const float* __restrict__ b2,
                        const float* __restrict__ W3, const float* __restrict__ b3,
                        float* __restrict__ bands) {
  const int j = blockIdx.y;
  __shared__ float w2s[4096];
  __shared__ float w1s[64], b1s[64], b2s[64], w3s[64];
  for (int i = threadIdx.x; i < 4096; i += 256) w2s[i] = W2[j * 4096 + i];
  if (threadIdx.x < 64) {
    w1s[threadIdx.x] = W1[j * 64 + threadIdx.x];
    b1s[threadIdx.x] = b1[j * 64 + threadIdx.x];
    b2s[threadIdx.x] = b2[j * 64 + threadIdx.x];
    w3s[threadIdx.x] = W3[j * 64 + threadIdx.x];
  }
  __syncthreads();
  const int k = blockIdx.x * 256 + threadIdx.x;
  if (k >= 2049) return;
  const float xc = x[8 * k];
  float h1[64];
  #pragma unroll
  for (int o = 0; o < 64; ++o) h1[o] = tanhf(w1s[o] * xc + b1s[o]);
  float outv = b3[j];
  for (int o = 0; o < 64; ++o) {
    float a0 = 0.f, a1 = 0.f, a2 = 0.f, a3 = 0.f;
    #pragma unroll
    for (int c = 0; c < 64; c += 4) {
      a0 += w2s[o * 64 + c] * h1[c];
      a1 += w2s[o * 64 + c + 1] * h1[c + 1];
      a2 += w2s[o * 64 + c + 2] * h1[c + 2];
      a3 += w2s[o * 64 + c + 3] * h1[c + 3];
    }
    outv += w3s[o] * tanhf(b2s[o] + ((a0 + a1) + (a2 + a3)));
  }
  bands[j * 2049 + k] = outv;
}

// fused interp chain -> a in fp32, length 16385
__global__ void k_interp(const float* __restrict__ bands, float* __restrict__ af32) {
  __shared__ float s1[4097];
  __shared__ float s2[8193];
  const int tid = threadIdx.x;
  const float* bd0 = bands;
  const float* bd1 = bands + 2049;
  const float* bd2 = bands + 2 * 2049;
  for (int i = tid; i < 4097; i += 1024) {
    float v = (i & 1) ? 0.5f * (bd0[i >> 1] + bd0[(i >> 1) + 1]) : bd0[i >> 1];
    if (i >= 512 && i < 2561) v = bd1[i - 512];
    s1[i] = v;
  }
  __syncthreads();
  for (int i = tid; i < 8193; i += 1024) {
    float v = (i & 1) ? 0.5f * (s1[i >> 1] + s1[(i >> 1) + 1]) : s1[i >> 1];
    if (i >= 1024 && i < 3073) v = bd2[i - 1024];
    s2[i] = v;
  }
  __syncthreads();
  for (int i = tid; i < 16385; i += 1024) {
    float v = (i & 1) ? 0.5f * (s2[i >> 1] + s2[(i >> 1) + 1]) : s2[i >> 1];
    af32[i] = v;
  }
}

// A-hat: fused pack+stage1 (c0=(af[2j],af[2j+1]), c1=(af[2j+8192],af[2j+8193]),
// c2=delta(j==0)*(af[16384],0), c3=0), then stages 1..6, then rfft unpack.
__global__ __launch_bounds__(NTHR, 4) void k_ahat(const float* __restrict__ af32,
                                                  const float2* __restrict__ tw,
                                                  const float2* __restrict__ tau,
                                                  float2* __restrict__ Ahat) {
  __shared__ float2 Z[ZPAD];
  const int tid = threadIdx.x;
  #pragma unroll 1
  for (int r = 0; r < 4; ++r) {
    const int j = tid + r * NTHR;
    const int z0 = ZIDX(j);
    float2 c0 = make_float2(af32[2 * j], af32[2 * j + 1]);
    float2 c1 = make_float2(af32[2 * j + 8192], af32[2 * j + 8193]);
    float2 c2 = (j == 0) ? make_float2(af32[16384], 0.f) : make_float2(0.f, 0.f);
    float2 w1 = tw[j];
    float2 w2 = cmul(w1, w1), w3 = cmul(w1, w2);
    float2 t0 = cadd(c0, c2), t1 = csub(c0, c2);
    float2 t2 = c1;
    float2 t3 = make_float2(c1.y, -c1.x);            // -i*c1
    Z[z0]           = cadd(t0, t2);
    Z[z0 + 4420]    = cmul(w1, cadd(t1, t3));
    Z[z0 + 2*4420]  = cmul(w2, csub(t0, t2));
    Z[z0 + 3*4420]  = cmul(w3, csub(t1, t3));
  }
  __syncthreads();
  fft_fwd_rest(Z, tw, tid);
  const float sc = 1.0f / 16384.0f;
  for (int k = tid; k <= 16384; k += NTHR) {
    float2 A;
    if (k == 0) {
      float2 z0 = Z[ZIDX(0)];
      A = make_float2((z0.x + z0.y) * sc, 0.f);
    } else if (k == 16384) {
      float2 z0 = Z[ZIDX(0)];
      A = make_float2((z0.x - z0.y) * sc, 0.f);
    } else if (k == 8192) {
      float2 z8 = Z[ZIDX(rev4_14(8192))];
      A = make_float2(z8.x * sc, -z8.y * sc);
    } else {
      const int kc = 16384 - k;
      float2 Zk = Z[ZIDX(rev4_14(k))];
      float2 Zc = Z[ZIDX(rev4_14(kc))];
      float2 E = make_float2(0.5f * (Zk.x + Zc.x), 0.5f * (Zk.y - Zc.y));
      float2 D = make_float2(Zk.x - Zc.x, Zk.y + Zc.y);
      float2 O = make_float2(0.5f * D.y, -0.5f * D.x);
      float2 tk = tau[k];
      float2 tO = cmul(tk, O);
      A = make_float2((E.x + tO.x) * sc, (E.y + tO.y) * sc);
    }
    Ahat[k] = A;
  }
}

// Main conv kernel: fused pack+stage1, stages 1..6, spectral multiply in
// rev-slot (mm) order, inverse stages, fused final-stage+output.
__global__ __launch_bounds__(NTHR, 4) void k_conv(const float* __restrict__ u,
                                                  const float2* __restrict__ Ahat,
                                                  const float2* __restrict__ tw,
                                                  const float2* __restrict__ tau,
                                                  float* __restrict__ out) {
  __shared__ float2 Z[ZPAD];
  const int tid = threadIdx.x;
  const int b = blockIdx.x;
  const float* ub = u + (size_t)b * NN;

  // fused pack + fwd stage 0 (Q=4096): utilde has c1=c2=0,
  // c3=(ub[2j],ub[2j+1]), c0=delta(j==0)*(ub[8192],0) ->
  // Z[j]=c0+c3; Z[j+Q]=w1(c0+ic3); Z[j+2Q]=w2(c0-c3); Z[j+3Q]=w3(c0-ic3).
  #pragma unroll 1
  for (int r = 0; r < 4; ++r) {
    const int j = tid + r * NTHR;
    const int z0 = ZIDX(j);
    float2 c3 = make_float2(ub[2 * j], ub[2 * j + 1]);
    float2 c0 = (j == 0) ? make_float2(ub[8192], 0.f) : make_float2(0.f, 0.f);
    float2 w1 = tw[j];
    float2 w2 = cmul(w1, w1), w3 = cmul(w1, w2);
    float2 ic3 = make_float2(-c3.y, c3.x);           // +i*c3
    Z[z0]           = cadd(c0, c3);
    Z[z0 + 4420]    = cmul(w1, cadd(c0, ic3));
    Z[z0 + 2*4420]  = cmul(w2, csub(c0, c3));
    Z[z0 + 3*4420]  = cmul(w3, csub(c0, ic3));
  }
  __syncthreads();

  fft_fwd_rest(Z, tw, tid);

  // spectral multiply, rev-slot order: mm with mm&3 in {0,1} <-> k=rev(mm)<8192
  // (bijective). Owned side Z[ZIDX(mm)] is lane-coalesced; partner scattered.
  for (int i = tid; i < 8192; i += NTHR) {
    const int mm = ((i >> 1) << 2) | (i & 1);
    if (mm == 0) {
      float2 z0 = Z[ZIDX(0)];
      float X0 = z0.x + z0.y;
      float XN = z0.x - z0.y;
      float Y0 = X0 * Ahat[0].x;
      float YN = XN * Ahat[16384].x;
      Z[ZIDX(0)] = make_float2(0.5f * (Y0 + YN), 0.5f * (Y0 - YN));
      const int r8 = ZIDX(2);                        // rev(8192) = 2
      float2 z8 = Z[r8];
      float2 X8 = make_float2(z8.x, -z8.y);
      float2 Y8 = cmul(X8, Ahat[8192]);
      Z[r8] = make_float2(Y8.x, -Y8.y);
    } else {
      const int k = rev4_14(mm);                     // k in (0,8192)
      const int kc = 16384 - k;
      const int rk = ZIDX(mm), rkc = ZIDX(rev4_14(kc));
      float2 Zk = Z[rk], Zc = Z[rkc];
      float2 E = make_float2(0.5f * (Zk.x + Zc.x), 0.5f * (Zk.y - Zc.y));
      float2 D = make_float2(Zk.x - Zc.x, Zk.y + Zc.y);
      float2 O = make_float2(0.5f * D.y, -0.5f * D.x);
      float2 tk = tau[k];
      float2 tO = cmul(tk, O);
      float2 Xk = make_float2(E.x + tO.x, E.y + tO.y);
      float2 Xc = make_float2(E.x - tO.x, -(E.y - tO.y));
      float2 Yk = cmul(Xk, Ahat[k]);
      float2 Y2 = cmul(Xc, Ahat[kc]);
      float2 Ep = make_float2(0.5f * (Yk.x + Y2.x), 0.5f * (Yk.y - Y2.y));
      float2 D2 = make_float2(0.5f * (Yk.x - Y2.x), 0.5f * (Yk.y + Y2.y));
      float2 tb = make_float2(tk.x, -tk.y);
      float2 Op = cmul(tb, D2);
      Z[rk]  = make_float2(Ep.x - Op.y, Ep.y + Op.x);
      Z[rkc] = make_float2(Ep.x + Op.y, -Ep.y + Op.x);
    }
  }
  __syncthreads();

  fft_inv_rest(Z, tw, tid);

  // fused final inv stage (Q=4096) + output: natural Z[j]=s0+s2 -> ob[2j..],
  // natural Z[4096]=s1+s3 (j==0) -> ob[8192]. Discarded quarters not stored.
  float* ob = out + (size_t)b * NN;
  #pragma unroll 1
  for (int r = 0; r < 4; ++r) {
    const int j = tid + r * NTHR;
    const int z0 = ZIDX(j);
    float2 w1 = tw[j]; w1.y = -w1.y;
    float2 w2 = cmul(w1, w1), w3 = cmul(w1, w2);
    float2 u0 = Z[z0];
    float2 u1 = cmul(w1, Z[z0 + 4420]);
    float2 u2 = cmul(w2, Z[z0 + 2*4420]);
    float2 u3 = cmul(w3, Z[z0 + 3*4420]);
    float2 s0 = cadd(u0, u2), s2 = cadd(u1, u3);
    float2 zj = cadd(s0, s2);
    ob[2 * j]     = zj.x;
    ob[2 * j + 1] = zj.y;
    if (j == 0) {
      float2 s1 = csub(u0, u2);
      float2 s3 = make_float2(-(u1.y - u3.y), u1.x - u3.x);
      ob[8192] = s1.x + s3.x;
    }
  }
}

extern "C" void kernel_launch(void* const* d_in, const int* in_sizes, int n_in,
                              void* d_out, int out_size, void* d_ws, size_t ws_size,
                              hipStream_t stream) {
  (void)in_sizes; (void)n_in; (void)out_size; (void)ws_size;
  const float* u  = (const float*)d_in[0];
  const float* x  = (const float*)d_in[1];
  const float* W1 = (const float*)d_in[2];
  const float* b1 = (const float*)d_in[3];
  const float* W2 = (const float*)d_in[4];
  const float* b2 = (const float*)d_in[5];
  const float* W3 = (const float*)d_in[6];
  const float* b3 = (const float*)d_in[7];
  float* out = (float*)d_out;
  char*  ws  = (char*)d_ws;

  float*  bands = (float*)(ws + OFF_BANDS);
  float*  af32  = (float*)(ws + OFF_AF32);
  float2* Ahat  = (float2*)(ws + OFF_AHAT);
  float2* tw    = (float2*)(ws + OFF_TW);
  float2* tau   = (float2*)(ws + OFF_TAU);

  k_tw<<<65, 256, 0, stream>>>(tw, tau);
  k_bands<<<dim3(9, 3), 256, 0, stream>>>(x, W1, b1, W2, b2, W3, b3, bands);
  k_interp<<<1, 1024, 0, stream>>>(bands, af32);
  k_ahat<<<1, NTHR, 0, stream>>>(af32, tw, tau, Ahat);
  k_conv<<<1024, NTHR, 0, stream>>>(u, Ahat, tw, tau, out);
}

// Round 16
// 196.243 us; speedup vs baseline: 1.4021x; 1.4021x over previous
//
#include <hip/hip_runtime.h>

#define NN  8193       // output cols per row; u length
#define FN  16384      // complex FFT length (real conv length 32768)
#define NTHR 1024      // threads per FFT block

// LDS swizzle-pad (R12/R14-verified): injective. Max ZIDX(16383) = 17676.
#define ZIDX(i) ((i) + ((i) >> 4) + ((i) >> 6) + ((i) >> 10))
#define ZPAD 17680

// workspace byte offsets (256-aligned)
#define OFF_BANDS 0u        // 3*2049*4
#define OFF_AF32  24832u    // 16385*4
#define OFF_AHAT  90624u    // 16385*8
#define OFF_TW    221952u   // 4096*8 = 32768 (w_N^e, e in [0,4096) — L1-resident)
#define OFF_TAU   320256u   // 16385*8 (exp(-i pi k/N))
#define OFF_REVP  451584u   // 8192*4 (ushort2 rev-pair table, L2-resident)

__device__ __forceinline__ float2 cmul(float2 a, float2 b) {
  return make_float2(a.x * b.x - a.y * b.y, a.x * b.y + a.y * b.x);
}
__device__ __forceinline__ float2 cadd(float2 a, float2 b) { return make_float2(a.x + b.x, a.y + b.y); }
__device__ __forceinline__ float2 csub(float2 a, float2 b) { return make_float2(a.x - b.x, a.y - b.y); }

// base-4 digit reversal of 7 digits (14 bits)
__device__ __forceinline__ int rev4_14(int k) {
  int r = 0;
  #pragma unroll
  for (int i = 0; i < 7; ++i) { r = (r << 2) | (k & 3); k >>= 2; }
  return r;
}

// Single radix-4 stage with affine swizzled offsets (R14-verified).
template<int Q, int M, bool INV>
__device__ __forceinline__ void stage4(float2* Z, const float2* __restrict__ tw,
                                       int tid) {
  constexpr int ZO = (Q == 1024) ? 1105 : (Q == 256) ? 276
                   : (Q == 64)   ? 69   : (Q == 16)  ? 17  : 4;
  #pragma unroll 1
  for (int r = 0; r < FN / 4 / NTHR; ++r) {
    const int idx = tid + r * NTHR;
    const int j  = idx & (Q - 1);
    const int b1 = idx / Q;
    const int z0 = ZIDX(b1 * 4 * Q + j);
    float2 w1 = tw[j * M];
    if (INV) w1.y = -w1.y;
    const float2 w2 = cmul(w1, w1);
    const float2 w3 = cmul(w1, w2);
    if (!INV) {
      float2 c0 = Z[z0], c1 = Z[z0 + ZO], c2 = Z[z0 + 2 * ZO], c3 = Z[z0 + 3 * ZO];
      float2 t0 = cadd(c0, c2), t1 = csub(c0, c2), t2 = cadd(c1, c3);
      float2 t3 = make_float2(c1.y - c3.y, -(c1.x - c3.x));   // -i*(c1-c3)
      Z[z0]          = cadd(t0, t2);
      Z[z0 + ZO]     = cmul(w1, cadd(t1, t3));
      Z[z0 + 2 * ZO] = cmul(w2, csub(t0, t2));
      Z[z0 + 3 * ZO] = cmul(w3, csub(t1, t3));
    } else {
      float2 u0 = Z[z0];
      float2 u1 = cmul(w1, Z[z0 + ZO]);
      float2 u2 = cmul(w2, Z[z0 + 2 * ZO]);
      float2 u3 = cmul(w3, Z[z0 + 3 * ZO]);
      float2 s0 = cadd(u0, u2), s1 = csub(u0, u2), s2 = cadd(u1, u3);
      float2 s3 = make_float2(-(u1.y - u3.y), u1.x - u3.x);   // +i*(u1-u3)
      Z[z0]          = cadd(s0, s2);
      Z[z0 + ZO]     = cadd(s1, s3);
      Z[z0 + 2 * ZO] = csub(s0, s2);
      Z[z0 + 3 * ZO] = csub(s1, s3);
    }
  }
}

// stage 6 (Q=1): all twiddles = 1
__device__ __forceinline__ void s6_fwd(float2* Z, int tid) {
  #pragma unroll 1
  for (int m = tid; m < FN / 4; m += NTHR) {
    const int zb = 4 * m + (m >> 2) + (m >> 4) + (m >> 8);
    float2 c0 = Z[zb], c1 = Z[zb + 1], c2 = Z[zb + 2], c3 = Z[zb + 3];
    float2 t0 = cadd(c0, c2), t1 = csub(c0, c2), t2 = cadd(c1, c3);
    float2 t3 = make_float2(c1.y - c3.y, -(c1.x - c3.x));
    Z[zb]     = cadd(t0, t2);
    Z[zb + 1] = cadd(t1, t3);
    Z[zb + 2] = csub(t0, t2);
    Z[zb + 3] = csub(t1, t3);
  }
}
__device__ __forceinline__ void s6_inv(float2* Z, int tid) {
  #pragma unroll 1
  for (int m = tid; m < FN / 4; m += NTHR) {
    const int zb = 4 * m + (m >> 2) + (m >> 4) + (m >> 8);
    float2 u0 = Z[zb], u1 = Z[zb + 1], u2 = Z[zb + 2], u3 = Z[zb + 3];
    float2 s0 = cadd(u0, u2), s1 = csub(u0, u2), s2 = cadd(u1, u3);
    float2 s3 = make_float2(-(u1.y - u3.y), u1.x - u3.x);
    Z[zb]     = cadd(s0, s2);
    Z[zb + 1] = cadd(s1, s3);
    Z[zb + 2] = csub(s0, s2);
    Z[zb + 3] = csub(s1, s3);
  }
}

// forward stages 1..6 (after the fused first stage)
__device__ void fft_fwd_rest(float2* Z, const float2* __restrict__ tw, int tid) {
  stage4<1024, 4, false>(Z, tw, tid);   __syncthreads();
  stage4<256, 16, false>(Z, tw, tid);   __syncthreads();
  stage4<64, 64, false>(Z, tw, tid);    __syncthreads();
  stage4<16, 256, false>(Z, tw, tid);   __syncthreads();
  stage4<4, 1024, false>(Z, tw, tid);   __syncthreads();
  s6_fwd(Z, tid);                       __syncthreads();
}
// inverse stages up to (but excluding) the final Q=4096 stage
__device__ void fft_inv_rest(float2* Z, const float2* __restrict__ tw, int tid) {
  s6_inv(Z, tid);                       __syncthreads();
  stage4<4, 1024, true>(Z, tw, tid);    __syncthreads();
  stage4<16, 256, true>(Z, tw, tid);    __syncthreads();
  stage4<64, 64, true>(Z, tw, tid);     __syncthreads();
  stage4<256, 16, true>(Z, tw, tid);    __syncthreads();
  stage4<1024, 4, true>(Z, tw, tid);    __syncthreads();
}

// twiddle tables + rev-pair table
__global__ void k_tw(float2* __restrict__ tw, float2* __restrict__ tau,
                     ushort2* __restrict__ revp) {
  const int i = blockIdx.x * 256 + threadIdx.x;
  if (i < 4096) {
    const float ang = -6.283185307179586f * (float)i / 16384.0f;
    tw[i] = make_float2(cosf(ang), sinf(ang));
  }
  if (i <= 16384) {
    const float ang = -3.1415926535897932f * (float)i / 16384.0f;
    tau[i] = make_float2(cosf(ang), sinf(ang));
  }
  if (i >= 1 && i < 8192) {
    revp[i] = make_ushort2((unsigned short)rev4_14(i),
                           (unsigned short)rev4_14(16384 - i));
  }
}

// ---------------- kernel a construction (unchanged) ----------
__global__ void k_bands(const float* __restrict__ x,
                        const float* __restrict__ W1, const float* __restrict__ b1,
                        const float* __restrict__ W2, const float* __restrict__ b2,
                        const float* __restrict__ W3, const float* __restrict__ b3,
                        float* __restrict__ bands) {
  const int j = blockIdx.y;
  __shared__ float w2s[4096];
  __shared__ float w1s[64], b1s[64], b2s[64], w3s[64];
  for (int i = threadIdx.x; i < 4096; i += 256) w2s[i] = W2[j * 4096 + i];
  if (threadIdx.x < 64) {
    w1s[threadIdx.x] = W1[j * 64 + threadIdx.x];
    b1s[threadIdx.x] = b1[j * 64 + threadIdx.x];
    b2s[threadIdx.x] = b2[j * 64 + threadIdx.x];
    w3s[threadIdx.x] = W3[j * 64 + threadIdx.x];
  }
  __syncthreads();
  const int k = blockIdx.x * 256 + threadIdx.x;
  if (k >= 2049) return;
  const float xc = x[8 * k];
  float h1[64];
  #pragma unroll
  for (int o = 0; o < 64; ++o) h1[o] = tanhf(w1s[o] * xc + b1s[o]);
  float outv = b3[j];
  for (int o = 0; o < 64; ++o) {
    float a0 = 0.f, a1 = 0.f, a2 = 0.f, a3 = 0.f;
    #pragma unroll
    for (int c = 0; c < 64; c += 4) {
      a0 += w2s[o * 64 + c] * h1[c];
      a1 += w2s[o * 64 + c + 1] * h1[c + 1];
      a2 += w2s[o * 64 + c + 2] * h1[c + 2];
      a3 += w2s[o * 64 + c + 3] * h1[c + 3];
    }
    outv += w3s[o] * tanhf(b2s[o] + ((a0 + a1) + (a2 + a3)));
  }
  bands[j * 2049 + k] = outv;
}

// fused interp chain -> a in fp32, length 16385
__global__ void k_interp(const float* __restrict__ bands, float* __restrict__ af32) {
  __shared__ float s1[4097];
  __shared__ float s2[8193];
  const int tid = threadIdx.x;
  const float* bd0 = bands;
  const float* bd1 = bands + 2049;
  const float* bd2 = bands + 2 * 2049;
  for (int i = tid; i < 4097; i += 1024) {
    float v = (i & 1) ? 0.5f * (bd0[i >> 1] + bd0[(i >> 1) + 1]) : bd0[i >> 1];
    if (i >= 512 && i < 2561) v = bd1[i - 512];
    s1[i] = v;
  }
  __syncthreads();
  for (int i = tid; i < 8193; i += 1024) {
    float v = (i & 1) ? 0.5f * (s1[i >> 1] + s1[(i >> 1) + 1]) : s1[i >> 1];
    if (i >= 1024 && i < 3073) v = bd2[i - 1024];
    s2[i] = v;
  }
  __syncthreads();
  for (int i = tid; i < 16385; i += 1024) {
    float v = (i & 1) ? 0.5f * (s2[i >> 1] + s2[(i >> 1) + 1]) : s2[i >> 1];
    af32[i] = v;
  }
}

// A-hat: fused pack+stage1, stages 1..6, rfft unpack (R15-verified).
__global__ __launch_bounds__(NTHR, 4) void k_ahat(const float* __restrict__ af32,
                                                  const float2* __restrict__ tw,
                                                  const float2* __restrict__ tau,
                                                  float2* __restrict__ Ahat) {
  __shared__ float2 Z[ZPAD];
  const int tid = threadIdx.x;
  #pragma unroll 1
  for (int r = 0; r < 4; ++r) {
    const int j = tid + r * NTHR;
    const int z0 = ZIDX(j);
    float2 c0 = make_float2(af32[2 * j], af32[2 * j + 1]);
    float2 c1 = make_float2(af32[2 * j + 8192], af32[2 * j + 8193]);
    float2 c2 = (j == 0) ? make_float2(af32[16384], 0.f) : make_float2(0.f, 0.f);
    float2 w1 = tw[j];
    float2 w2 = cmul(w1, w1), w3 = cmul(w1, w2);
    float2 t0 = cadd(c0, c2), t1 = csub(c0, c2);
    float2 t2 = c1;
    float2 t3 = make_float2(c1.y, -c1.x);            // -i*c1
    Z[z0]           = cadd(t0, t2);
    Z[z0 + 4420]    = cmul(w1, cadd(t1, t3));
    Z[z0 + 2*4420]  = cmul(w2, csub(t0, t2));
    Z[z0 + 3*4420]  = cmul(w3, csub(t1, t3));
  }
  __syncthreads();
  fft_fwd_rest(Z, tw, tid);
  const float sc = 1.0f / 16384.0f;
  for (int k = tid; k <= 16384; k += NTHR) {
    float2 A;
    if (k == 0) {
      float2 z0 = Z[ZIDX(0)];
      A = make_float2((z0.x + z0.y) * sc, 0.f);
    } else if (k == 16384) {
      float2 z0 = Z[ZIDX(0)];
      A = make_float2((z0.x - z0.y) * sc, 0.f);
    } else if (k == 8192) {
      float2 z8 = Z[ZIDX(rev4_14(8192))];
      A = make_float2(z8.x * sc, -z8.y * sc);
    } else {
      const int kc = 16384 - k;
      float2 Zk = Z[ZIDX(rev4_14(k))];
      float2 Zc = Z[ZIDX(rev4_14(kc))];
      float2 E = make_float2(0.5f * (Zk.x + Zc.x), 0.5f * (Zk.y - Zc.y));
      float2 D = make_float2(Zk.x - Zc.x, Zk.y + Zc.y);
      float2 O = make_float2(0.5f * D.y, -0.5f * D.x);
      float2 tk = tau[k];
      float2 tO = cmul(tk, O);
      A = make_float2((E.x + tO.x) * sc, (E.y + tO.y) * sc);
    }
    Ahat[k] = A;
  }
}

// Main conv kernel: fused pack+stage1 (R15-verified), stages 1..6,
// spectral multiply in NATURAL k order (R14-verified; coalesced Ahat/tau,
// revp table replaces in-loop digit reversal), inverse stages,
// fused final-stage+output (R15-verified).
__global__ __launch_bounds__(NTHR, 4) void k_conv(const float* __restrict__ u,
                                                  const float2* __restrict__ Ahat,
                                                  const float2* __restrict__ tw,
                                                  const float2* __restrict__ tau,
                                                  const ushort2* __restrict__ revp,
                                                  float* __restrict__ out) {
  __shared__ float2 Z[ZPAD];
  const int tid = threadIdx.x;
  const int b = blockIdx.x;
  const float* ub = u + (size_t)b * NN;

  // fused pack + fwd stage 0 (Q=4096): utilde has c1=c2=0,
  // c3=(ub[2j],ub[2j+1]), c0=delta(j==0)*(ub[8192],0).
  #pragma unroll 1
  for (int r = 0; r < 4; ++r) {
    const int j = tid + r * NTHR;
    const int z0 = ZIDX(j);
    float2 c3 = make_float2(ub[2 * j], ub[2 * j + 1]);
    float2 c0 = (j == 0) ? make_float2(ub[8192], 0.f) : make_float2(0.f, 0.f);
    float2 w1 = tw[j];
    float2 w2 = cmul(w1, w1), w3 = cmul(w1, w2);
    float2 ic3 = make_float2(-c3.y, c3.x);           // +i*c3
    Z[z0]           = cadd(c0, c3);
    Z[z0 + 4420]    = cmul(w1, cadd(c0, ic3));
    Z[z0 + 2*4420]  = cmul(w2, csub(c0, c3));
    Z[z0 + 3*4420]  = cmul(w3, csub(c0, ic3));
  }
  __syncthreads();

  fft_fwd_rest(Z, tw, tid);

  // spectral multiply, natural k order (pairs bijective, no sync)
  for (int i = tid; i < 8192; i += NTHR) {
    if (i == 0) {
      float2 z0 = Z[ZIDX(0)];
      float X0 = z0.x + z0.y;
      float XN = z0.x - z0.y;
      float Y0 = X0 * Ahat[0].x;
      float YN = XN * Ahat[16384].x;
      Z[ZIDX(0)] = make_float2(0.5f * (Y0 + YN), 0.5f * (Y0 - YN));
      const int r8 = ZIDX(2);                        // rev(8192) = 2
      float2 z8 = Z[r8];
      float2 X8 = make_float2(z8.x, -z8.y);
      float2 Y8 = cmul(X8, Ahat[8192]);
      Z[r8] = make_float2(Y8.x, -Y8.y);
    } else {
      const int k = i, kc = 16384 - i;
      const ushort2 rp = revp[i];
      const int rk = ZIDX((int)rp.x), rkc = ZIDX((int)rp.y);
      float2 Zk = Z[rk], Zc = Z[rkc];
      float2 E = make_float2(0.5f * (Zk.x + Zc.x), 0.5f * (Zk.y - Zc.y));
      float2 D = make_float2(Zk.x - Zc.x, Zk.y + Zc.y);
      float2 O = make_float2(0.5f * D.y, -0.5f * D.x);
      float2 tk = tau[k];
      float2 tO = cmul(tk, O);
      float2 Xk = make_float2(E.x + tO.x, E.y + tO.y);
      float2 Xc = make_float2(E.x - tO.x, -(E.y - tO.y));
      float2 Yk = cmul(Xk, Ahat[k]);
      float2 Y2 = cmul(Xc, Ahat[kc]);
      float2 Ep = make_float2(0.5f * (Yk.x + Y2.x), 0.5f * (Yk.y - Y2.y));
      float2 D2 = make_float2(0.5f * (Yk.x - Y2.x), 0.5f * (Yk.y + Y2.y));
      float2 tb = make_float2(tk.x, -tk.y);
      float2 Op = cmul(tb, D2);
      Z[rk]  = make_float2(Ep.x - Op.y, Ep.y + Op.x);
      Z[rkc] = make_float2(Ep.x + Op.y, -Ep.y + Op.x);
    }
  }
  __syncthreads();

  fft_inv_rest(Z, tw, tid);

  // fused final inv stage (Q=4096) + output
  float* ob = out + (size_t)b * NN;
  #pragma unroll 1
  for (int r = 0; r < 4; ++r) {
    const int j = tid + r * NTHR;
    const int z0 = ZIDX(j);
    float2 w1 = tw[j]; w1.y = -w1.y;
    float2 w2 = cmul(w1, w1), w3 = cmul(w1, w2);
    float2 u0 = Z[z0];
    float2 u1 = cmul(w1, Z[z0 + 4420]);
    float2 u2 = cmul(w2, Z[z0 + 2*4420]);
    float2 u3 = cmul(w3, Z[z0 + 3*4420]);
    float2 s0 = cadd(u0, u2), s2 = cadd(u1, u3);
    float2 zj = cadd(s0, s2);
    ob[2 * j]     = zj.x;
    ob[2 * j + 1] = zj.y;
    if (j == 0) {
      float2 s1 = csub(u0, u2);
      float2 s3 = make_float2(-(u1.y - u3.y), u1.x - u3.x);
      ob[8192] = s1.x + s3.x;
    }
  }
}

extern "C" void kernel_launch(void* const* d_in, const int* in_sizes, int n_in,
                              void* d_out, int out_size, void* d_ws, size_t ws_size,
                              hipStream_t stream) {
  (void)in_sizes; (void)n_in; (void)out_size; (void)ws_size;
  const float* u  = (const float*)d_in[0];
  const float* x  = (const float*)d_in[1];
  const float* W1 = (const float*)d_in[2];
  const float* b1 = (const float*)d_in[3];
  const float* W2 = (const float*)d_in[4];
  const float* b2 = (const float*)d_in[5];
  const float* W3 = (const float*)d_in[6];
  const float* b3 = (const float*)d_in[7];
  float* out = (float*)d_out;
  char*  ws  = (char*)d_ws;

  float*   bands = (float*)(ws + OFF_BANDS);
  float*   af32  = (float*)(ws + OFF_AF32);
  float2*  Ahat  = (float2*)(ws + OFF_AHAT);
  float2*  tw    = (float2*)(ws + OFF_TW);
  float2*  tau   = (float2*)(ws + OFF_TAU);
  ushort2* revp  = (ushort2*)(ws + OFF_REVP);

  k_tw<<<65, 256, 0, stream>>>(tw, tau, revp);
  k_bands<<<dim3(9, 3), 256, 0, stream>>>(x, W1, b1, W2, b2, W3, b3, bands);
  k_interp<<<1, 1024, 0, stream>>>(bands, af32);
  k_ahat<<<1, NTHR, 0, stream>>>(af32, tw, tau, Ahat);
  k_conv<<<1024, NTHR, 0, stream>>>(u, Ahat, tw, tau, revp, out);
}